// Round 18
// baseline (134.971 us; speedup 1.0000x reference)
//
#include <hip/hip_runtime.h>
#include <hip/hip_bf16.h>
#include <stdint.h>

// Problem constants (UniformStrideAttention): B=2, S=2048, D=768, H=12, HD=64, STRIDE=8
#define H_   12
#define S_   2048
#define D_   768
#define HD_  64
#define MS_  256   // S_/8 compressed strided keys per head

typedef __bf16 bf16_8 __attribute__((ext_vector_type(8)));
typedef float  f32_4  __attribute__((ext_vector_type(4)));

typedef __attribute__((address_space(1))) void* gas_ptr;
typedef __attribute__((address_space(3))) void* las_ptr;

__device__ __forceinline__ void g2l16(const void* g, void* l) {
  __builtin_amdgcn_global_load_lds((gas_ptr)g, (las_ptr)l, 16, 0, 0);
}

__device__ __forceinline__ f32_4 mfma16(bf16_8 a, bf16_8 b, f32_4 c) {
  return __builtin_amdgcn_mfma_f32_16x16x32_bf16(a, b, c, 0, 0, 0);
}

__device__ __forceinline__ bf16_8 ld8(const __hip_bfloat16* p) {
  return *reinterpret_cast<const bf16_8*>(p);
}

// ---------------------------------------------------------------------------
// Fused fp32 -> bf16 convert for all three GEMM inputs (x, qkv_w, out_w).
// Destinations are CONTIGUOUS in ws (xb | w1b | w2b), so output index == t.
// ---------------------------------------------------------------------------
__global__ __launch_bounds__(256) void cvt3_f32_bf16(
    const float* __restrict__ a, const float* __restrict__ b,
    const float* __restrict__ c, __hip_bfloat16* __restrict__ out,
    int na4, int nb4) {
  const int t = blockIdx.x * 256 + threadIdx.x;
  float4 f;
  if (t < na4)            f = reinterpret_cast<const float4*>(a)[t];
  else if (t < na4 + nb4) f = reinterpret_cast<const float4*>(b)[t - na4];
  else                    f = reinterpret_cast<const float4*>(c)[t - na4 - nb4];
  union { __hip_bfloat16 h[4]; ushort4 u; } p;
  p.h[0] = __float2bfloat16(f.x);
  p.h[1] = __float2bfloat16(f.y);
  p.h[2] = __float2bfloat16(f.z);
  p.h[3] = __float2bfloat16(f.w);
  reinterpret_cast<ushort4*>(out)[t] = p.u;
}

// ---------------------------------------------------------------------------
// C[M,N] = A[M,K] * B[N,K]^T + bias[N]   (bf16 in, fp32 MFMA accum, fp32 bias)
// R13 state (frozen): BM=64 x BN tiles + T1 XCD swizzle; gemm1 (MODE 1)
// keeps the neutral-but-harmless 2-phase dbuf. NO setprio here: m190 showed
// setprio hurts barrier-lockstep GEMMs.
// LDS [buf][kk][row][32] half-tiles: 64B row stride (2-way alias = free).
// MODE 0 (BN=128): QKV epilogue -> q/k/v row-major [bh][s][d] + compressed
//   Ks[bh][s/8][d] (t==1, s%8==0) + VsT[bh][d][s/8] (t==2, s%8==0).
// MODE 1 (BN=64): plain epilogue -> OF[M,N] fp32.
// ---------------------------------------------------------------------------
template <int MODE, int BN>
__global__ __launch_bounds__(256, 4) void gemm_bt(
    const __hip_bfloat16* __restrict__ A, const __hip_bfloat16* __restrict__ B,
    const float* __restrict__ bias,
    __hip_bfloat16* __restrict__ O0, __hip_bfloat16* __restrict__ O1,
    __hip_bfloat16* __restrict__ O2, __hip_bfloat16* __restrict__ O3,
    __hip_bfloat16* __restrict__ O4, float* __restrict__ OF,
    int M, int N, int K) {
  constexpr int NTJ  = BN / 32;
  constexpr int HB   = BN * 32;         // elems per kk half of sB
  constexpr int DB   = (MODE == 1) ? 2 : 1;   // dbuf on gemm1 only
  constexpr int ABUF = 64 * 64;         // elems per sA buffer
  constexpr int BBUF = BN * 64;         // elems per sB buffer
  __shared__ __bf16 sA[DB * ABUF];      // [buf][kk][64][32]
  __shared__ __bf16 sB[DB * BBUF];      // [buf][kk][BN][32]
  const int tid  = threadIdx.x;
  const int lane = tid & 63;
  const int wv   = tid >> 6;

  // T1 XCD swizzle: hw id -> work id so each XCD owns a contiguous run.
  const int nwg  = gridDim.x * gridDim.y;
  const int hw   = blockIdx.y * gridDim.x + blockIdx.x;
  const int swz  = (hw & 7) * (nwg >> 3) + (hw >> 3);
  const int bx   = swz % gridDim.x;
  const int by   = swz / gridDim.x;

  const int m0 = by * 64;
  const int n0 = bx * BN;
  const int wr = (wv >> 1) * 32;        // wave row offset (2 x 32 rows)
  const int wc = (wv & 1) * (BN / 2);   // wave col offset

  f32_4 acc[2][NTJ] = {};

  // staging: 4 lanes per row, 16B each -> 64B (=32 elems) of a row per call
  const __hip_bfloat16* aS = A + (size_t)(m0 + (tid >> 2)) * K + ((tid & 3) << 3);
  const __hip_bfloat16* bS = B + (size_t)(n0 + (tid >> 2)) * K + ((tid & 3) << 3);
  const size_t half = (size_t)64 * K;   // row 64..127 of the B tile (BN=128)
  __bf16* dA = &sA[tid * 8];
  __bf16* dB = &sB[tid * 8];

  const int fr = lane & 15;
  const int kq = (lane >> 4) << 3;

  auto stage = [&](int k0, int buf) {
    const __hip_bfloat16* a = aS + k0;
    const __hip_bfloat16* b = bS + k0;
    __bf16* da = dA + buf * ABUF;
    __bf16* db = dB + buf * BBUF;
    g2l16(a,      da);
    g2l16(a + 32, da + 2048);
    g2l16(b,      db);
    if constexpr (BN == 128) {
      g2l16(b + half,      db + 2048);
      g2l16(b + 32,        db + 4096);
      g2l16(b + half + 32, db + 4096 + 2048);
    } else {
      g2l16(b + 32, db + 2048);         // kk1 half of the 64-row tile
    }
  };

  auto compute = [&](const __bf16* bA, const __bf16* bB) {
    // kk-interleaved: per k-half load 2+NTJ frags, consume, move on.
#pragma unroll
    for (int kk = 0; kk < 2; ++kk) {
      bf16_8 af[2], bfm[NTJ];
#pragma unroll
      for (int t = 0; t < 2; ++t)
        af[t] = *reinterpret_cast<const bf16_8*>(
            &bA[kk * 2048 + (wr + t * 16 + fr) * 32 + kq]);
#pragma unroll
      for (int t = 0; t < NTJ; ++t)
        bfm[t] = *reinterpret_cast<const bf16_8*>(
            &bB[kk * HB + (wc + t * 16 + fr) * 32 + kq]);
#pragma unroll
      for (int ti = 0; ti < 2; ++ti)
#pragma unroll
        for (int tj = 0; tj < NTJ; ++tj)
          acc[ti][tj] = mfma16(af[ti], bfm[tj], acc[ti][tj]);
    }
  };

  if constexpr (DB == 1) {
    // single-buffered, two barriers/step (R9-exact path for gemm0)
    for (int k0 = 0; k0 < K; k0 += 64) {
      stage(k0, 0);
      __syncthreads();
      compute(sA, sB);
      __syncthreads();
    }
  } else {
    // T3 minimum 2-phase: prefetch next tile before computing current;
    // one barrier/step (its implicit vmcnt(0) drain overlaps compute).
    stage(0, 0);
    __syncthreads();
    int cur = 0;
    for (int k0 = 0; k0 < K; k0 += 64) {
      if (k0 + 64 < K) stage(k0 + 64, cur ^ 1);
      compute(&sA[cur * ABUF], &sB[cur * BBUF]);
      __syncthreads();
      cur ^= 1;
    }
  }

  // epilogue: C/D layout col=lane&15, row=(lane>>4)*4+reg
  const int crow = (lane >> 4) << 2;
  const int ccol = lane & 15;
#pragma unroll
  for (int ti = 0; ti < 2; ++ti) {
    const int gmb = m0 + wr + ti * 16 + crow;
#pragma unroll
    for (int tj = 0; tj < NTJ; ++tj) {
      const int gn = n0 + wc + tj * 16 + ccol;
      const float bv = bias[gn];
      if (MODE == 0) {
        const int t   = gn / D_;
        const int rem = gn - t * D_;
        const int hh = rem >> 6, dd = rem & 63;
        __hip_bfloat16* dst = (t == 0) ? O0 : (t == 1) ? O1 : O2;
#pragma unroll
        for (int r = 0; r < 4; ++r) {
          const int gm = gmb + r;
          const int bb = gm >> 11, ss = gm & (S_ - 1);
          const __hip_bfloat16 hv = __float2bfloat16(acc[ti][tj][r] + bv);
          dst[(((size_t)(bb * H_ + hh) << 11) + ss) * HD_ + dd] = hv;
          if (r == 0 && (gmb & 7) == 0) {
            if (t == 1)        // compressed K rows for coalesced strided reads
              O4[(((size_t)(bb * H_ + hh)) * MS_ + (ss >> 3)) * HD_ + dd] = hv;
            else if (t == 2)   // compressed V^T (d-major) for strided PV
              O3[((size_t)(bb * H_ + hh) * HD_ + dd) * MS_ + (ss >> 3)] = hv;
          }
        }
      } else {
#pragma unroll
        for (int r = 0; r < 4; ++r)
          OF[(size_t)(gmb + r) * D_ + gn] = acc[ti][tj][r] + bv;
      }
    }
  }
}

// ---------------------------------------------------------------------------
// MFMA strided attention, NO-RESCALE softmax, 4-WAVE K-SPLIT, 32-ROW TASKS,
// long-tasks-first (R17 state, ties best 134.6).
// R18 delta: T5 s_setprio(1) around the per-chunk MFMA+exp2+PV cluster.
// m191: +4-7% on attn where resident waves sit at DIFFERENT phases (our
// waves run independent chunk chains until one terminal barrier; ~6
// blocks/CU of mixed ages). m190: hurts lockstep GEMMs -> GEMMs untouched.
// Pure scheduler hint, zero correctness risk.
// ---------------------------------------------------------------------------
__global__ __launch_bounds__(256) void attn_mfma(
    const __hip_bfloat16* __restrict__ Q, const __hip_bfloat16* __restrict__ Kb,
    const __hip_bfloat16* __restrict__ Ks, const __hip_bfloat16* __restrict__ Vr,
    const __hip_bfloat16* __restrict__ VsT, __hip_bfloat16* __restrict__ ctx) {
  __shared__ __bf16 pt[4][32 * 40];
  __shared__ float ox[3][64][40];   // parts 1-3: 16 O + 4 L per row-set x2
  const int lane = threadIdx.x & 63;
  const int part = threadIdx.x >> 6;        // K-split quarter 0..3
  // T1 swizzle: contiguous 192-task (3-head) runs per XCD
  const int nwg  = gridDim.x;               // 1536 (% 8 == 0 -> bijective)
  const int hw   = blockIdx.x;
  const int task = (hw & 7) * (nwg >> 3) + (hw >> 3);
  const int bh   = task >> 6;               // 64 qtiles per head
  const int i0   = (63 - (task & 63)) << 5; // reversed: long tasks first
  const int lr   = lane & 15;
  const int quad = lane >> 4;
  const float SC = 0.125f * 1.44269504088896340736f;  // 1/sqrt(64)*log2(e)

  const __hip_bfloat16* Kh  = Kb  + ((size_t)bh << 11) * HD_;
  const __hip_bfloat16* Ksh = Ks  + (size_t)bh * MS_ * HD_;
  const __hip_bfloat16* Vrh = Vr  + ((size_t)bh << 11) * HD_;
  const __hip_bfloat16* Vsh = VsT + (size_t)bh * HD_ * MS_;
  __bf16* ptw = pt[part];

  // --- band loads (parts 2/3 only), issued first to hide latency ---
  bf16_8 vfb[4], kb_[2][2];
  int jb = 0;
  if (part >= 2) {
    jb = (part == 3) ? ((i0 >= 8) ? i0 - 8 : 0) : (i0 + 8);
    const __bf16* Vrb = reinterpret_cast<const __bf16*>(Vrh);
#pragma unroll
    for (int ct = 0; ct < 4; ++ct)
#pragma unroll
      for (int e = 0; e < 8; ++e) {
        const int j  = jb + quad * 8 + e;
        const int jr = (j < S_) ? j : (S_ - 1);   // clamp; masked via P=0
        vfb[ct][e] = Vrb[(size_t)jr * HD_ + ct * 16 + lr];
      }
#pragma unroll
    for (int t = 0; t < 2; ++t) {
      const int j  = jb + t * 16 + lr;
      const int jr = (j < S_) ? j : (S_ - 1);
      const __hip_bfloat16* kp = Kh + (size_t)jr * HD_ + quad * 8;
      kb_[t][0] = ld8(kp);
      kb_[t][1] = ld8(kp + 32);
    }
  }

  // Q A-frags, both row sets: rows i0+lr (A) and i0+16+lr (B), k=quad*8(+32)
  const __hip_bfloat16* qpA = Q + (((size_t)bh << 11) + i0 + lr) * HD_ + quad * 8;
  const bf16_8 qa0 = ld8(qpA);
  const bf16_8 qa1 = ld8(qpA + 32);
  const __hip_bfloat16* qpB = qpA + (size_t)16 * HD_;
  const bf16_8 qb0 = ld8(qpB);
  const bf16_8 qb1 = ld8(qpB + 32);

  const __bf16 one = (__bf16)1.0f;
  const bf16_8 onesf = {one, one, one, one, one, one, one, one};

  f32_4 LA = {}, LB = {}, oA[4], oB[4];
#pragma unroll
  for (int ct = 0; ct < 4; ++ct) { oA[ct] = f32_4{0.f,0.f,0.f,0.f}; oB[ct] = f32_4{0.f,0.f,0.f,0.f}; }

  const int mmax = (i0 + 31) >> 3;
  const int nstr = (mmax >> 5) + 1;   // strided 32-key chunks (1..8)

  auto load_str = [&](int c, bf16_8 (&kf)[2][2], bf16_8 (&vf)[4]) {
    const int mb = c << 5;
#pragma unroll
    for (int t = 0; t < 2; ++t) {
      const __hip_bfloat16* kp = Ksh + (size_t)(mb + t * 16 + lr) * HD_ + quad * 8;
      kf[t][0] = ld8(kp);
      kf[t][1] = ld8(kp + 32);
    }
#pragma unroll
    for (int ct = 0; ct < 4; ++ct)
      vf[ct] = ld8(Vsh + (size_t)(ct * 16 + lr) * MS_ + mb + quad * 8);
  };

  // P transpose + PV for one 16-row set at pt-row offset ro (0=A, 16=B)
  auto softmax_pv = [&](int ro, f32_4& s0, f32_4& s1, const bf16_8 (&vf)[4],
                        f32_4 (&oac)[4], f32_4& La) {
#pragma unroll
    for (int r = 0; r < 4; ++r) {
      const int row = ro + quad * 4 + r;
      ptw[row * 40 + lr]      = (__bf16)__float2bfloat16(s0[r]);
      ptw[row * 40 + 16 + lr] = (__bf16)__float2bfloat16(s1[r]);
    }
    const bf16_8 pf = *reinterpret_cast<const bf16_8*>(&ptw[(ro + lr) * 40 + quad * 8]);
#pragma unroll
    for (int ct = 0; ct < 4; ++ct) oac[ct] = mfma16(pf, vf[ct], oac[ct]);
    La = mfma16(pf, onesf, La);
  };

  // --- this part's strided chunks (stride 4, prefetched); both row sets
  //     consume the SAME kf/vf (2x arithmetic per load) ---
  bf16_8 kf[2][2], vf[4], kf2[2][2], vf2[4];
  if (part < nstr) load_str(part, kf, vf);
  for (int c = part; c < nstr; c += 4) {
    const bool more = (c + 4 < nstr);
    if (more) load_str(c + 4, kf2, vf2);
    const int mb = c << 5;

    __builtin_amdgcn_s_setprio(1);   // T5: favor compute-ready wave
    // set A
    {
      f32_4 s0 = {}, s1 = {};
      s0 = mfma16(qa0, kf[0][0], s0);
      s0 = mfma16(qa1, kf[0][1], s0);
      s1 = mfma16(qa0, kf[1][0], s1);
      s1 = mfma16(qa1, kf[1][1], s1);
#pragma unroll
      for (int r = 0; r < 4; ++r) {
        const int i = i0 + quad * 4 + r;
        const bool v0 = ((mb + lr) << 3) <= i;
        const bool v1 = ((mb + 16 + lr) << 3) <= i;
        s0[r] = v0 ? exp2f(fminf(s0[r] * SC, 63.f)) : 0.f;
        s1[r] = v1 ? exp2f(fminf(s1[r] * SC, 63.f)) : 0.f;
      }
      softmax_pv(0, s0, s1, vf, oA, LA);
    }
    // set B
    {
      f32_4 s0 = {}, s1 = {};
      s0 = mfma16(qb0, kf[0][0], s0);
      s0 = mfma16(qb1, kf[0][1], s0);
      s1 = mfma16(qb0, kf[1][0], s1);
      s1 = mfma16(qb1, kf[1][1], s1);
#pragma unroll
      for (int r = 0; r < 4; ++r) {
        const int i = i0 + 16 + quad * 4 + r;
        const bool v0 = ((mb + lr) << 3) <= i;
        const bool v1 = ((mb + 16 + lr) << 3) <= i;
        s0[r] = v0 ? exp2f(fminf(s0[r] * SC, 63.f)) : 0.f;
        s1[r] = v1 ? exp2f(fminf(s1[r] * SC, 63.f)) : 0.f;
      }
      softmax_pv(16, s0, s1, vf, oB, LB);
    }
    __builtin_amdgcn_s_setprio(0);

    if (more) {
#pragma unroll
      for (int t = 0; t < 2; ++t) { kf[t][0] = kf2[t][0]; kf[t][1] = kf2[t][1]; }
#pragma unroll
      for (int ct = 0; ct < 4; ++ct) vf[ct] = vf2[ct];
    }
  }

  // --- bands: part 3 -> window A / rows A;  part 2 -> window B / rows B ---
  if (part == 3) {
    __builtin_amdgcn_s_setprio(1);
    f32_4 s0 = {}, s1 = {};
    s0 = mfma16(qa0, kb_[0][0], s0);
    s0 = mfma16(qa1, kb_[0][1], s0);
    s1 = mfma16(qa0, kb_[1][0], s1);
    s1 = mfma16(qa1, kb_[1][1], s1);
#pragma unroll
    for (int r = 0; r < 4; ++r) {
      const int i = i0 + quad * 4 + r;
      const int j0 = jb + lr, j1 = jb + 16 + lr;
      const bool v0 = (j0 == i || j0 == i - 1) && (j0 & 7);
      const bool v1 = (j1 == i || j1 == i - 1) && (j1 & 7);
      s0[r] = v0 ? exp2f(fminf(s0[r] * SC, 63.f)) : 0.f;
      s1[r] = v1 ? exp2f(fminf(s1[r] * SC, 63.f)) : 0.f;
    }
    softmax_pv(0, s0, s1, vfb, oA, LA);
    __builtin_amdgcn_s_setprio(0);
  } else if (part == 2) {
    __builtin_amdgcn_s_setprio(1);
    f32_4 s0 = {}, s1 = {};
    s0 = mfma16(qb0, kb_[0][0], s0);
    s0 = mfma16(qb1, kb_[0][1], s0);
    s1 = mfma16(qb0, kb_[1][0], s1);
    s1 = mfma16(qb1, kb_[1][1], s1);
#pragma unroll
    for (int r = 0; r < 4; ++r) {
      const int i = i0 + 16 + quad * 4 + r;
      const int j0 = jb + lr, j1 = jb + 16 + lr;
      const bool v0 = (j0 == i || j0 == i - 1) && (j0 & 7);
      const bool v1 = (j1 == i || j1 == i - 1) && (j1 & 7);
      s0[r] = v0 ? exp2f(fminf(s0[r] * SC, 63.f)) : 0.f;
      s1[r] = v1 ? exp2f(fminf(s1[r] * SC, 63.f)) : 0.f;
    }
    softmax_pv(16, s0, s1, vfb, oB, LB);
    __builtin_amdgcn_s_setprio(0);
  }

  // --- parts 1-3: dump partials; part 0: combine, normalize, write ---
  if (part) {
#pragma unroll
    for (int ct = 0; ct < 4; ++ct)
#pragma unroll
      for (int r = 0; r < 4; ++r) {
        ox[part - 1][lane][ct * 4 + r]      = oA[ct][r];
        ox[part - 1][lane][20 + ct * 4 + r] = oB[ct][r];
      }
#pragma unroll
    for (int r = 0; r < 4; ++r) {
      ox[part - 1][lane][16 + r] = LA[r];
      ox[part - 1][lane][36 + r] = LB[r];
    }
  }
  __syncthreads();

  if (!part) {
#pragma unroll
    for (int p = 0; p < 3; ++p) {
#pragma unroll
      for (int ct = 0; ct < 4; ++ct)
#pragma unroll
        for (int r = 0; r < 4; ++r) {
          oA[ct][r] += ox[p][lane][ct * 4 + r];
          oB[ct][r] += ox[p][lane][20 + ct * 4 + r];
        }
#pragma unroll
      for (int r = 0; r < 4; ++r) {
        LA[r] += ox[p][lane][16 + r];
        LB[r] += ox[p][lane][36 + r];
      }
    }

    const int b = bh / H_;
    const int h = bh - b * H_;
    f32_4 invA, invB;
#pragma unroll
    for (int r = 0; r < 4; ++r) { invA[r] = 1.f / LA[r]; invB[r] = 1.f / LB[r]; }
#pragma unroll
    for (int r = 0; r < 4; ++r) {
      const int iA = i0 + quad * 4 + r;
      __hip_bfloat16* cpA = ctx + ((size_t)(b * S_ + iA)) * D_ + h * HD_ + lr;
#pragma unroll
      for (int ct = 0; ct < 4; ++ct)
        cpA[ct * 16] = __float2bfloat16(oA[ct][r] * invA[r]);
      const int iB = iA + 16;
      __hip_bfloat16* cpB = ctx + ((size_t)(b * S_ + iB)) * D_ + h * HD_ + lr;
#pragma unroll
      for (int ct = 0; ct < 4; ++ct)
        cpB[ct * 16] = __float2bfloat16(oB[ct][r] * invB[r]);
    }
  }
}

// ---------------------------------------------------------------------------
extern "C" void kernel_launch(void* const* d_in, const int* in_sizes, int n_in,
                              void* d_out, int out_size, void* d_ws, size_t ws_size,
                              hipStream_t stream) {
  const float* x    = (const float*)d_in[0];  // [B,S,D]    fp32
  const float* qkvw = (const float*)d_in[1];  // [3D,D]     fp32
  const float* qkvb = (const float*)d_in[2];  // [3D]       fp32
  const float* outw = (const float*)d_in[3];  // [D,D]      fp32
  const float* outb = (const float*)d_in[4];  // [D]        fp32
  float* out = (float*)d_out;                 // [B,S,D]    fp32

  const size_t NX  = (size_t)2 * S_ * D_;     // 3,145,728
  const size_t NW1 = (size_t)3 * D_ * D_;     // 1,769,472
  const size_t NW2 = (size_t)D_ * D_;         //   589,824
  const size_t NVS = (size_t)2 * H_ * HD_ * MS_;  // 393,216

  __hip_bfloat16* xb  = (__hip_bfloat16*)d_ws;
  __hip_bfloat16* w1b = xb + NX;
  __hip_bfloat16* w2b = w1b + NW1;
  __hip_bfloat16* q   = w2b + NW2;
  __hip_bfloat16* k   = q + NX;
  __hip_bfloat16* vr  = k + NX;     // [bh][s][d] row-major v
  __hip_bfloat16* vst = vr + NX;    // [bh][64][256] compressed V^T
  __hip_bfloat16* ks  = vst + NVS;  // [bh][256][64] compressed K rows
  __hip_bfloat16* ctx = ks + NVS;   // [B,S,H*HD]
  // total ws: (5*NX + NW1 + NW2 + 2*NVS)*2 B ~= 37.3 MB

  // fused fp32 -> bf16 converts (xb|w1b|w2b contiguous)
  const int na4 = (int)(NX / 4), nb4 = (int)(NW1 / 4), nc4 = (int)(NW2 / 4);
  cvt3_f32_bf16<<<dim3((na4 + nb4 + nc4) / 256), 256, 0, stream>>>(
      x, qkvw, outw, xb, na4, nb4);

  // BM=64: grid 18 x 64 = 1152 blocks (4.5/CU), XCD-swizzled
  gemm_bt<0, 128><<<dim3(2304 / 128, 4096 / 64), 256, 0, stream>>>(
      xb, w1b, qkvb, q, k, vr, vst, ks, nullptr, 4096, 2304, 768);

  // 1536 tasks of 32 rows, 1 task per 4-wave block, XCD-swizzled,
  // long-tasks-first, T5 setprio on MFMA clusters
  attn_mfma<<<dim3(2 * H_ * S_ / 32), 256, 0, stream>>>(
      q, k, ks, vr, vst, ctx);

  // out-proj: BM=64 x BN=64 -> 768 blocks (3/CU), swizzled, 2-phase dbuf
  gemm_bt<1, 64><<<dim3(768 / 64, 4096 / 64), 256, 0, stream>>>(
      ctx, w2b, outb, nullptr, nullptr, nullptr, nullptr, nullptr,
      out, 4096, 768, 768);
}

// Round 19
// 134.239 us; speedup vs baseline: 1.0055x; 1.0055x over previous
//
#include <hip/hip_runtime.h>
#include <hip/hip_bf16.h>
#include <stdint.h>

// Problem constants (UniformStrideAttention): B=2, S=2048, D=768, H=12, HD=64, STRIDE=8
#define H_   12
#define S_   2048
#define D_   768
#define HD_  64
#define MS_  256   // S_/8 compressed strided keys per head

typedef __bf16 bf16_8 __attribute__((ext_vector_type(8)));
typedef float  f32_4  __attribute__((ext_vector_type(4)));

typedef __attribute__((address_space(1))) void* gas_ptr;
typedef __attribute__((address_space(3))) void* las_ptr;

__device__ __forceinline__ void g2l16(const void* g, void* l) {
  __builtin_amdgcn_global_load_lds((gas_ptr)g, (las_ptr)l, 16, 0, 0);
}

__device__ __forceinline__ f32_4 mfma16(bf16_8 a, bf16_8 b, f32_4 c) {
  return __builtin_amdgcn_mfma_f32_16x16x32_bf16(a, b, c, 0, 0, 0);
}

__device__ __forceinline__ bf16_8 ld8(const __hip_bfloat16* p) {
  return *reinterpret_cast<const bf16_8*>(p);
}

// ---------------------------------------------------------------------------
// Fused fp32 -> bf16 convert for all three GEMM inputs (x, qkv_w, out_w).
// Destinations are CONTIGUOUS in ws (xb | w1b | w2b), so output index == t.
// ---------------------------------------------------------------------------
__global__ __launch_bounds__(256) void cvt3_f32_bf16(
    const float* __restrict__ a, const float* __restrict__ b,
    const float* __restrict__ c, __hip_bfloat16* __restrict__ out,
    int na4, int nb4) {
  const int t = blockIdx.x * 256 + threadIdx.x;
  float4 f;
  if (t < na4)            f = reinterpret_cast<const float4*>(a)[t];
  else if (t < na4 + nb4) f = reinterpret_cast<const float4*>(b)[t - na4];
  else                    f = reinterpret_cast<const float4*>(c)[t - na4 - nb4];
  union { __hip_bfloat16 h[4]; ushort4 u; } p;
  p.h[0] = __float2bfloat16(f.x);
  p.h[1] = __float2bfloat16(f.y);
  p.h[2] = __float2bfloat16(f.z);
  p.h[3] = __float2bfloat16(f.w);
  reinterpret_cast<ushort4*>(out)[t] = p.u;
}

// ---------------------------------------------------------------------------
// C[M,N] = A[M,K] * B[N,K]^T + bias[N]   (bf16 in, fp32 MFMA accum, fp32 bias)
// Final state: BM=64 x BN tiles + T1 XCD swizzle; gemm1 (MODE 1) keeps the
// neutral-but-harmless 2-phase dbuf. No setprio (m190: hurts lockstep GEMMs).
// LDS [buf][kk][row][32] half-tiles: 64B row stride (2-way alias = free).
// MODE 0 (BN=128): QKV epilogue -> q/k/v row-major [bh][s][d] + compressed
//   Ks[bh][s/8][d] (t==1, s%8==0) + VsT[bh][d][s/8] (t==2, s%8==0).
// MODE 1 (BN=64): plain epilogue -> OF[M,N] fp32.
// ---------------------------------------------------------------------------
template <int MODE, int BN>
__global__ __launch_bounds__(256, 4) void gemm_bt(
    const __hip_bfloat16* __restrict__ A, const __hip_bfloat16* __restrict__ B,
    const float* __restrict__ bias,
    __hip_bfloat16* __restrict__ O0, __hip_bfloat16* __restrict__ O1,
    __hip_bfloat16* __restrict__ O2, __hip_bfloat16* __restrict__ O3,
    __hip_bfloat16* __restrict__ O4, float* __restrict__ OF,
    int M, int N, int K) {
  constexpr int NTJ  = BN / 32;
  constexpr int HB   = BN * 32;         // elems per kk half of sB
  constexpr int DB   = (MODE == 1) ? 2 : 1;   // dbuf on gemm1 only
  constexpr int ABUF = 64 * 64;         // elems per sA buffer
  constexpr int BBUF = BN * 64;         // elems per sB buffer
  __shared__ __bf16 sA[DB * ABUF];      // [buf][kk][64][32]
  __shared__ __bf16 sB[DB * BBUF];      // [buf][kk][BN][32]
  const int tid  = threadIdx.x;
  const int lane = tid & 63;
  const int wv   = tid >> 6;

  // T1 XCD swizzle: hw id -> work id so each XCD owns a contiguous run.
  const int nwg  = gridDim.x * gridDim.y;
  const int hw   = blockIdx.y * gridDim.x + blockIdx.x;
  const int swz  = (hw & 7) * (nwg >> 3) + (hw >> 3);
  const int bx   = swz % gridDim.x;
  const int by   = swz / gridDim.x;

  const int m0 = by * 64;
  const int n0 = bx * BN;
  const int wr = (wv >> 1) * 32;        // wave row offset (2 x 32 rows)
  const int wc = (wv & 1) * (BN / 2);   // wave col offset

  f32_4 acc[2][NTJ] = {};

  // staging: 4 lanes per row, 16B each -> 64B (=32 elems) of a row per call
  const __hip_bfloat16* aS = A + (size_t)(m0 + (tid >> 2)) * K + ((tid & 3) << 3);
  const __hip_bfloat16* bS = B + (size_t)(n0 + (tid >> 2)) * K + ((tid & 3) << 3);
  const size_t half = (size_t)64 * K;   // row 64..127 of the B tile (BN=128)
  __bf16* dA = &sA[tid * 8];
  __bf16* dB = &sB[tid * 8];

  const int fr = lane & 15;
  const int kq = (lane >> 4) << 3;

  auto stage = [&](int k0, int buf) {
    const __hip_bfloat16* a = aS + k0;
    const __hip_bfloat16* b = bS + k0;
    __bf16* da = dA + buf * ABUF;
    __bf16* db = dB + buf * BBUF;
    g2l16(a,      da);
    g2l16(a + 32, da + 2048);
    g2l16(b,      db);
    if constexpr (BN == 128) {
      g2l16(b + half,      db + 2048);
      g2l16(b + 32,        db + 4096);
      g2l16(b + half + 32, db + 4096 + 2048);
    } else {
      g2l16(b + 32, db + 2048);         // kk1 half of the 64-row tile
    }
  };

  auto compute = [&](const __bf16* bA, const __bf16* bB) {
    // kk-interleaved: per k-half load 2+NTJ frags, consume, move on.
#pragma unroll
    for (int kk = 0; kk < 2; ++kk) {
      bf16_8 af[2], bfm[NTJ];
#pragma unroll
      for (int t = 0; t < 2; ++t)
        af[t] = *reinterpret_cast<const bf16_8*>(
            &bA[kk * 2048 + (wr + t * 16 + fr) * 32 + kq]);
#pragma unroll
      for (int t = 0; t < NTJ; ++t)
        bfm[t] = *reinterpret_cast<const bf16_8*>(
            &bB[kk * HB + (wc + t * 16 + fr) * 32 + kq]);
#pragma unroll
      for (int ti = 0; ti < 2; ++ti)
#pragma unroll
        for (int tj = 0; tj < NTJ; ++tj)
          acc[ti][tj] = mfma16(af[ti], bfm[tj], acc[ti][tj]);
    }
  };

  if constexpr (DB == 1) {
    // single-buffered, two barriers/step
    for (int k0 = 0; k0 < K; k0 += 64) {
      stage(k0, 0);
      __syncthreads();
      compute(sA, sB);
      __syncthreads();
    }
  } else {
    // T3 minimum 2-phase: prefetch next tile before computing current;
    // one barrier/step (its implicit vmcnt(0) drain overlaps compute).
    stage(0, 0);
    __syncthreads();
    int cur = 0;
    for (int k0 = 0; k0 < K; k0 += 64) {
      if (k0 + 64 < K) stage(k0 + 64, cur ^ 1);
      compute(&sA[cur * ABUF], &sB[cur * BBUF]);
      __syncthreads();
      cur ^= 1;
    }
  }

  // epilogue: C/D layout col=lane&15, row=(lane>>4)*4+reg
  const int crow = (lane >> 4) << 2;
  const int ccol = lane & 15;
#pragma unroll
  for (int ti = 0; ti < 2; ++ti) {
    const int gmb = m0 + wr + ti * 16 + crow;
#pragma unroll
    for (int tj = 0; tj < NTJ; ++tj) {
      const int gn = n0 + wc + tj * 16 + ccol;
      const float bv = bias[gn];
      if (MODE == 0) {
        const int t   = gn / D_;
        const int rem = gn - t * D_;
        const int hh = rem >> 6, dd = rem & 63;
        __hip_bfloat16* dst = (t == 0) ? O0 : (t == 1) ? O1 : O2;
#pragma unroll
        for (int r = 0; r < 4; ++r) {
          const int gm = gmb + r;
          const int bb = gm >> 11, ss = gm & (S_ - 1);
          const __hip_bfloat16 hv = __float2bfloat16(acc[ti][tj][r] + bv);
          dst[(((size_t)(bb * H_ + hh) << 11) + ss) * HD_ + dd] = hv;
          if (r == 0 && (gmb & 7) == 0) {
            if (t == 1)        // compressed K rows for coalesced strided reads
              O4[(((size_t)(bb * H_ + hh)) * MS_ + (ss >> 3)) * HD_ + dd] = hv;
            else if (t == 2)   // compressed V^T (d-major) for strided PV
              O3[((size_t)(bb * H_ + hh) * HD_ + dd) * MS_ + (ss >> 3)] = hv;
          }
        }
      } else {
#pragma unroll
        for (int r = 0; r < 4; ++r)
          OF[(size_t)(gmb + r) * D_ + gn] = acc[ti][tj][r] + bv;
      }
    }
  }
}

// ---------------------------------------------------------------------------
// MFMA strided attention, NO-RESCALE softmax, 4-WAVE K-SPLIT, 32-ROW TASKS,
// long-tasks-first (R17 = session best, 134.6 us). Final state.
// Evidence trail: split+prefetch > de-split (+4.1) > no-prefetch (+14.3);
// 32 rows/task is the arithmetic-intensity saturation point (64 -> +10.2);
// XCD task swizzle -1.6; ordering and setprio neutral.
// LDS: pt 4x32x40 bf16 + ox 3x64x40 f32 = 40 KB.
// ---------------------------------------------------------------------------
__global__ __launch_bounds__(256) void attn_mfma(
    const __hip_bfloat16* __restrict__ Q, const __hip_bfloat16* __restrict__ Kb,
    const __hip_bfloat16* __restrict__ Ks, const __hip_bfloat16* __restrict__ Vr,
    const __hip_bfloat16* __restrict__ VsT, __hip_bfloat16* __restrict__ ctx) {
  __shared__ __bf16 pt[4][32 * 40];
  __shared__ float ox[3][64][40];   // parts 1-3: 16 O + 4 L per row-set x2
  const int lane = threadIdx.x & 63;
  const int part = threadIdx.x >> 6;        // K-split quarter 0..3
  // T1 swizzle: contiguous 192-task (3-head) runs per XCD
  const int nwg  = gridDim.x;               // 1536 (% 8 == 0 -> bijective)
  const int hw   = blockIdx.x;
  const int task = (hw & 7) * (nwg >> 3) + (hw >> 3);
  const int bh   = task >> 6;               // 64 qtiles per head
  const int i0   = (63 - (task & 63)) << 5; // reversed: long tasks first
  const int lr   = lane & 15;
  const int quad = lane >> 4;
  const float SC = 0.125f * 1.44269504088896340736f;  // 1/sqrt(64)*log2(e)

  const __hip_bfloat16* Kh  = Kb  + ((size_t)bh << 11) * HD_;
  const __hip_bfloat16* Ksh = Ks  + (size_t)bh * MS_ * HD_;
  const __hip_bfloat16* Vrh = Vr  + ((size_t)bh << 11) * HD_;
  const __hip_bfloat16* Vsh = VsT + (size_t)bh * HD_ * MS_;
  __bf16* ptw = pt[part];

  // --- band loads (parts 2/3 only), issued first to hide latency ---
  // part 3: window A base max(i0-8,0) for rows A; part 2: window B base
  // i0+8 for rows B. Both 8-aligned 32-key windows.
  bf16_8 vfb[4], kb_[2][2];
  int jb = 0;
  if (part >= 2) {
    jb = (part == 3) ? ((i0 >= 8) ? i0 - 8 : 0) : (i0 + 8);
    const __bf16* Vrb = reinterpret_cast<const __bf16*>(Vrh);
#pragma unroll
    for (int ct = 0; ct < 4; ++ct)
#pragma unroll
      for (int e = 0; e < 8; ++e) {
        const int j  = jb + quad * 8 + e;
        const int jr = (j < S_) ? j : (S_ - 1);   // clamp; masked via P=0
        vfb[ct][e] = Vrb[(size_t)jr * HD_ + ct * 16 + lr];
      }
#pragma unroll
    for (int t = 0; t < 2; ++t) {
      const int j  = jb + t * 16 + lr;
      const int jr = (j < S_) ? j : (S_ - 1);
      const __hip_bfloat16* kp = Kh + (size_t)jr * HD_ + quad * 8;
      kb_[t][0] = ld8(kp);
      kb_[t][1] = ld8(kp + 32);
    }
  }

  // Q A-frags, both row sets: rows i0+lr (A) and i0+16+lr (B), k=quad*8(+32)
  const __hip_bfloat16* qpA = Q + (((size_t)bh << 11) + i0 + lr) * HD_ + quad * 8;
  const bf16_8 qa0 = ld8(qpA);
  const bf16_8 qa1 = ld8(qpA + 32);
  const __hip_bfloat16* qpB = qpA + (size_t)16 * HD_;
  const bf16_8 qb0 = ld8(qpB);
  const bf16_8 qb1 = ld8(qpB + 32);

  const __bf16 one = (__bf16)1.0f;
  const bf16_8 onesf = {one, one, one, one, one, one, one, one};

  f32_4 LA = {}, LB = {}, oA[4], oB[4];
#pragma unroll
  for (int ct = 0; ct < 4; ++ct) { oA[ct] = f32_4{0.f,0.f,0.f,0.f}; oB[ct] = f32_4{0.f,0.f,0.f,0.f}; }

  const int mmax = (i0 + 31) >> 3;
  const int nstr = (mmax >> 5) + 1;   // strided 32-key chunks (1..8)

  auto load_str = [&](int c, bf16_8 (&kf)[2][2], bf16_8 (&vf)[4]) {
    const int mb = c << 5;
#pragma unroll
    for (int t = 0; t < 2; ++t) {
      const __hip_bfloat16* kp = Ksh + (size_t)(mb + t * 16 + lr) * HD_ + quad * 8;
      kf[t][0] = ld8(kp);
      kf[t][1] = ld8(kp + 32);
    }
#pragma unroll
    for (int ct = 0; ct < 4; ++ct)
      vf[ct] = ld8(Vsh + (size_t)(ct * 16 + lr) * MS_ + mb + quad * 8);
  };

  // P transpose + PV for one 16-row set at pt-row offset ro (0=A, 16=B)
  auto softmax_pv = [&](int ro, f32_4& s0, f32_4& s1, const bf16_8 (&vf)[4],
                        f32_4 (&oac)[4], f32_4& La) {
#pragma unroll
    for (int r = 0; r < 4; ++r) {
      const int row = ro + quad * 4 + r;
      ptw[row * 40 + lr]      = (__bf16)__float2bfloat16(s0[r]);
      ptw[row * 40 + 16 + lr] = (__bf16)__float2bfloat16(s1[r]);
    }
    const bf16_8 pf = *reinterpret_cast<const bf16_8*>(&ptw[(ro + lr) * 40 + quad * 8]);
#pragma unroll
    for (int ct = 0; ct < 4; ++ct) oac[ct] = mfma16(pf, vf[ct], oac[ct]);
    La = mfma16(pf, onesf, La);
  };

  // --- this part's strided chunks (stride 4, prefetched); both row sets
  //     consume the SAME kf/vf (2x arithmetic per load) ---
  bf16_8 kf[2][2], vf[4], kf2[2][2], vf2[4];
  if (part < nstr) load_str(part, kf, vf);
  for (int c = part; c < nstr; c += 4) {
    const bool more = (c + 4 < nstr);
    if (more) load_str(c + 4, kf2, vf2);
    const int mb = c << 5;

    // set A
    {
      f32_4 s0 = {}, s1 = {};
      s0 = mfma16(qa0, kf[0][0], s0);
      s0 = mfma16(qa1, kf[0][1], s0);
      s1 = mfma16(qa0, kf[1][0], s1);
      s1 = mfma16(qa1, kf[1][1], s1);
#pragma unroll
      for (int r = 0; r < 4; ++r) {
        const int i = i0 + quad * 4 + r;
        const bool v0 = ((mb + lr) << 3) <= i;
        const bool v1 = ((mb + 16 + lr) << 3) <= i;
        s0[r] = v0 ? exp2f(fminf(s0[r] * SC, 63.f)) : 0.f;
        s1[r] = v1 ? exp2f(fminf(s1[r] * SC, 63.f)) : 0.f;
      }
      softmax_pv(0, s0, s1, vf, oA, LA);
    }
    // set B
    {
      f32_4 s0 = {}, s1 = {};
      s0 = mfma16(qb0, kf[0][0], s0);
      s0 = mfma16(qb1, kf[0][1], s0);
      s1 = mfma16(qb0, kf[1][0], s1);
      s1 = mfma16(qb1, kf[1][1], s1);
#pragma unroll
      for (int r = 0; r < 4; ++r) {
        const int i = i0 + 16 + quad * 4 + r;
        const bool v0 = ((mb + lr) << 3) <= i;
        const bool v1 = ((mb + 16 + lr) << 3) <= i;
        s0[r] = v0 ? exp2f(fminf(s0[r] * SC, 63.f)) : 0.f;
        s1[r] = v1 ? exp2f(fminf(s1[r] * SC, 63.f)) : 0.f;
      }
      softmax_pv(16, s0, s1, vf, oB, LB);
    }

    if (more) {
#pragma unroll
      for (int t = 0; t < 2; ++t) { kf[t][0] = kf2[t][0]; kf[t][1] = kf2[t][1]; }
#pragma unroll
      for (int ct = 0; ct < 4; ++ct) vf[ct] = vf2[ct];
    }
  }

  // --- bands: part 3 -> window A / rows A;  part 2 -> window B / rows B ---
  if (part == 3) {
    f32_4 s0 = {}, s1 = {};
    s0 = mfma16(qa0, kb_[0][0], s0);
    s0 = mfma16(qa1, kb_[0][1], s0);
    s1 = mfma16(qa0, kb_[1][0], s1);
    s1 = mfma16(qa1, kb_[1][1], s1);
#pragma unroll
    for (int r = 0; r < 4; ++r) {
      const int i = i0 + quad * 4 + r;
      const int j0 = jb + lr, j1 = jb + 16 + lr;
      const bool v0 = (j0 == i || j0 == i - 1) && (j0 & 7);
      const bool v1 = (j1 == i || j1 == i - 1) && (j1 & 7);
      s0[r] = v0 ? exp2f(fminf(s0[r] * SC, 63.f)) : 0.f;
      s1[r] = v1 ? exp2f(fminf(s1[r] * SC, 63.f)) : 0.f;
    }
    softmax_pv(0, s0, s1, vfb, oA, LA);
  } else if (part == 2) {
    f32_4 s0 = {}, s1 = {};
    s0 = mfma16(qb0, kb_[0][0], s0);
    s0 = mfma16(qb1, kb_[0][1], s0);
    s1 = mfma16(qb0, kb_[1][0], s1);
    s1 = mfma16(qb1, kb_[1][1], s1);
#pragma unroll
    for (int r = 0; r < 4; ++r) {
      const int i = i0 + 16 + quad * 4 + r;
      const int j0 = jb + lr, j1 = jb + 16 + lr;
      const bool v0 = (j0 == i || j0 == i - 1) && (j0 & 7);
      const bool v1 = (j1 == i || j1 == i - 1) && (j1 & 7);
      s0[r] = v0 ? exp2f(fminf(s0[r] * SC, 63.f)) : 0.f;
      s1[r] = v1 ? exp2f(fminf(s1[r] * SC, 63.f)) : 0.f;
    }
    softmax_pv(16, s0, s1, vfb, oB, LB);
  }

  // --- parts 1-3: dump partials; part 0: combine, normalize, write ---
  if (part) {
#pragma unroll
    for (int ct = 0; ct < 4; ++ct)
#pragma unroll
      for (int r = 0; r < 4; ++r) {
        ox[part - 1][lane][ct * 4 + r]      = oA[ct][r];
        ox[part - 1][lane][20 + ct * 4 + r] = oB[ct][r];
      }
#pragma unroll
    for (int r = 0; r < 4; ++r) {
      ox[part - 1][lane][16 + r] = LA[r];
      ox[part - 1][lane][36 + r] = LB[r];
    }
  }
  __syncthreads();

  if (!part) {
#pragma unroll
    for (int p = 0; p < 3; ++p) {
#pragma unroll
      for (int ct = 0; ct < 4; ++ct)
#pragma unroll
        for (int r = 0; r < 4; ++r) {
          oA[ct][r] += ox[p][lane][ct * 4 + r];
          oB[ct][r] += ox[p][lane][20 + ct * 4 + r];
        }
#pragma unroll
      for (int r = 0; r < 4; ++r) {
        LA[r] += ox[p][lane][16 + r];
        LB[r] += ox[p][lane][36 + r];
      }
    }

    const int b = bh / H_;
    const int h = bh - b * H_;
    f32_4 invA, invB;
#pragma unroll
    for (int r = 0; r < 4; ++r) { invA[r] = 1.f / LA[r]; invB[r] = 1.f / LB[r]; }
#pragma unroll
    for (int r = 0; r < 4; ++r) {
      const int iA = i0 + quad * 4 + r;
      __hip_bfloat16* cpA = ctx + ((size_t)(b * S_ + iA)) * D_ + h * HD_ + lr;
#pragma unroll
      for (int ct = 0; ct < 4; ++ct)
        cpA[ct * 16] = __float2bfloat16(oA[ct][r] * invA[r]);
      const int iB = iA + 16;
      __hip_bfloat16* cpB = ctx + ((size_t)(b * S_ + iB)) * D_ + h * HD_ + lr;
#pragma unroll
      for (int ct = 0; ct < 4; ++ct)
        cpB[ct * 16] = __float2bfloat16(oB[ct][r] * invB[r]);
    }
  }
}

// ---------------------------------------------------------------------------
extern "C" void kernel_launch(void* const* d_in, const int* in_sizes, int n_in,
                              void* d_out, int out_size, void* d_ws, size_t ws_size,
                              hipStream_t stream) {
  const float* x    = (const float*)d_in[0];  // [B,S,D]    fp32
  const float* qkvw = (const float*)d_in[1];  // [3D,D]     fp32
  const float* qkvb = (const float*)d_in[2];  // [3D]       fp32
  const float* outw = (const float*)d_in[3];  // [D,D]      fp32
  const float* outb = (const float*)d_in[4];  // [D]        fp32
  float* out = (float*)d_out;                 // [B,S,D]    fp32

  const size_t NX  = (size_t)2 * S_ * D_;     // 3,145,728
  const size_t NW1 = (size_t)3 * D_ * D_;     // 1,769,472
  const size_t NW2 = (size_t)D_ * D_;         //   589,824
  const size_t NVS = (size_t)2 * H_ * HD_ * MS_;  // 393,216

  __hip_bfloat16* xb  = (__hip_bfloat16*)d_ws;
  __hip_bfloat16* w1b = xb + NX;
  __hip_bfloat16* w2b = w1b + NW1;
  __hip_bfloat16* q   = w2b + NW2;
  __hip_bfloat16* k   = q + NX;
  __hip_bfloat16* vr  = k + NX;     // [bh][s][d] row-major v
  __hip_bfloat16* vst = vr + NX;    // [bh][64][256] compressed V^T
  __hip_bfloat16* ks  = vst + NVS;  // [bh][256][64] compressed K rows
  __hip_bfloat16* ctx = ks + NVS;   // [B,S,H*HD]
  // total ws: (5*NX + NW1 + NW2 + 2*NVS)*2 B ~= 37.3 MB

  // fused fp32 -> bf16 converts (xb|w1b|w2b contiguous)
  const int na4 = (int)(NX / 4), nb4 = (int)(NW1 / 4), nc4 = (int)(NW2 / 4);
  cvt3_f32_bf16<<<dim3((na4 + nb4 + nc4) / 256), 256, 0, stream>>>(
      x, qkvw, outw, xb, na4, nb4);

  // BM=64: grid 18 x 64 = 1152 blocks (4.5/CU), XCD-swizzled
  gemm_bt<0, 128><<<dim3(2304 / 128, 4096 / 64), 256, 0, stream>>>(
      xb, w1b, qkvb, q, k, vr, vst, ks, nullptr, 4096, 2304, 768);

  // 1536 tasks of 32 rows, 1 task per 4-wave block, XCD-swizzled,
  // long-tasks-first
  attn_mfma<<<dim3(2 * H_ * S_ / 32), 256, 0, stream>>>(
      q, k, ks, vr, vst, ctx);

  // out-proj: BM=64 x BN=64 -> 768 blocks (3/CU), swizzled, 2-phase dbuf
  gemm_bt<1, 64><<<dim3(768 / 64, 4096 / 64), 256, 0, stream>>>(
      ctx, w2b, outb, nullptr, nullptr, nullptr, nullptr, nullptr,
      out, 4096, 768, 768);
}